// Round 5
// baseline (170.790 us; speedup 1.0000x reference)
//
#include <hip/hip_runtime.h>
#include <math.h>

// CRITICAL: ban FMA contraction file-wide. 1-ulp iou shifts flip near-tie
// argmaxes vs numpy's correctly-rounded ref (rounds 2-4, absmax 69).
#pragma clang fp contract(off)

// Shapes: B=64, N=100, A=8732.
// Out layout (f32 flat): [0,BA) labels | [BA,5BA) boxes | [5BA,6BA) mask
//
// ROUND 5: kill the tail-quantization with the minimal-risk half-row split.
// r2 (LDS) and r4 (scalar table) both measured 63.0us -> data path is not
// the limiter; the 2240-block grid vs 2048-block capacity leaves a full
// task-time tail (span 2t, occupancy 45-48%). New wave unit = 32 rows x 2
// halves (lanes 0-31: gts [0,50) of rows r..r+31; lanes 32-63: gts [50,100)
// of the same rows). 17,464 wave-tasks over exactly 8192 resident wave
// slots (2048 blocks x 4 waves, no padding) -> 2-or-3 tasks/slot -> span
// 1.5 row-times. Row state merges with one shfl_xor(32) (r3-validated
// packed (iou_bits<<32)|(NN-bi) argmax = max iou then smallest n = numpy
// first-max). Column trigger moved OUT of the hot loop into a second bit
// mask (cm) replayed per chunk: hot loop is branchless; cm is a superset
// of true column winners (scurf = deflated lower bound, stale reads safe),
// extra submissions idempotent under atomicMax.
//
// colmax u64[B*N]: init by prior (prior_bits<<32 | 0: low=0 loses ties to
// genuine submissions low>=1), atomicMax'd by iou, consumed by encode
// (fused, colmax in ws) or scatter (fallback, colmax in out's boxes region).
// tab f32[B*N*8] {gx,gy,gz,gw, ag, scurf, 0,0}: in out's boxes region after
// the fallback-colmax slot (only read by iou; encode overwrites last).

#define AA 8732
#define NN 100
#define BB 64
#define NTILE 35              // ceil(AA/256) for encode grid
#define NWT 17464             // BB*AA*2/64 wave-tasks (exact, no padding)
#define EPS_F 1e-6f
#define OVR_FLAG 0x10000
#define POS_BIT  0x8000
// qa = inter*v_rcp(uni): rel err <= ~1.8e-7. DEFL=1-5e-7 deflation makes all
// filters rigorous one-sided bounds (HW-validated rounds 8/10/11).
#define DEFL 0.9999995f
#define RT_SEED 1e-38f        // > 0: (qa >= rt) implies qa > 0 (validated r3)

__constant__ int FM_SIZE[6] = {38, 19, 10, 5, 3, 1};
__constant__ int FM_NF[6]   = {4, 6, 6, 6, 4, 4};
__constant__ int FM_OFF[6]  = {0, 5776, 7942, 8542, 8692, 8728};

__device__ __forceinline__ void geom(const float4 axy, const float4 g,
                                     float area_a, float ag,
                                     float& inter, float& uni) {
    float ltx = fmaxf(axy.x, g.x);
    float lty = fmaxf(axy.y, g.y);
    float rbx = fminf(axy.z, g.z);
    float rby = fminf(axy.w, g.w);
    float w = fmaxf(rbx - ltx, 0.0f);
    float h = fmaxf(rby - lty, 0.0f);
    inter = w * h;
    uni = area_a + ag - inter;       // uni >= max area > 0 always
}

// ---------------------------------------------------------------------------
// Prior: per (b,n), rcp-approx max IoU over the <=30 center-cell anchors,
// deflated => SAFE lower bound of the column max. Writes colmax init AND the
// 32B record table {g, ag, scurf_seed}.
// ---------------------------------------------------------------------------
__global__ void prior_kernel(const float4* __restrict__ gt_boxes,
                             const float4* __restrict__ anchors_xyxy,
                             unsigned long long* __restrict__ colmax,
                             float4* __restrict__ tab4) {
    const int b = blockIdx.x;
    const int n = threadIdx.x;
    if (n >= NN) return;
    float4 g = gt_boxes[b * NN + n];
    float ag = (g.z - g.x) * (g.w - g.y);
    float cx = (g.x + g.z) * 0.5f;
    float cy = (g.y + g.w) * 0.5f;
    float best = 0.0f;
    for (int f = 0; f < 6; f++) {
        int s = FM_SIZE[f];
        int j = (int)(cx * (float)s); j = j < s - 1 ? j : s - 1;
        int i = (int)(cy * (float)s); i = i < s - 1 ? i : s - 1;
        int base = FM_OFF[f] + (i * s + j) * FM_NF[f];
        for (int k = 0; k < FM_NF[f]; k++) {
            float4 an = anchors_xyxy[base + k];
            float area_a = (an.z - an.x) * (an.w - an.y);
            float inter, uni;
            geom(an, g, area_a, ag, inter, uni);
            best = fmaxf(best, inter * __builtin_amdgcn_rcpf(uni));
        }
    }
    float defl = best * DEFL;        // <= colM*(1-3.2e-7): safe lower bound
    colmax[b * NN + n] = ((unsigned long long)__float_as_uint(defl)) << 32;
    tab4[(b * NN + n) * 2]     = g;
    tab4[(b * NN + n) * 2 + 1] = make_float4(ag, defl, 0.0f, 0.0f);
}

// ---------------------------------------------------------------------------
// 25-gt chunk of a half-row: branchless. Builds row-record mask rm (vs
// running deflated rt) and column-candidate mask cm (vs table scurf).
// ---------------------------------------------------------------------------
__device__ __forceinline__ void chunk25(
        const float4 axy, const float area_a,
        const float4* __restrict__ tb, const int nbase,
        float& rt, unsigned& rm, unsigned& cm)
{
    #pragma unroll 5
    for (int i = 0; i < 25; i++) {
        const int n = nbase + i;
        float4 g = tb[n * 2];
        float4 q = tb[n * 2 + 1];  // .x=ag, .y=scurf (stale = superset, safe)
        float inter, uni;
        geom(axy, g, area_a, q.x, inter, uni);
        float qa = inter * __builtin_amdgcn_rcpf(uni);
        bool r = (qa >= rt);                         // row near-record
        rt = fmaxf(rt, qa * DEFL);
        rm |= (r ? 1u : 0u) << i;
        cm |= ((qa >= q.y) ? 1u : 0u) << i;          // column candidate
    }
}

// ---------------------------------------------------------------------------
// Half-row iou pass. 2048 blocks x 256 = 8192 waves (exact resident fit,
// launch_bounds(256,8)). Wave-task t: rows [32t, 32t+32); lane = (row
// offset lane&31) x (half h=lane>>5, gts [50h, 50h+50)). Slot s runs tasks
// [s*NWT>>13, (s+1)*NWT>>13) — 2 or 3 tasks, statically balanced.
// Per half: 2 branchless chunk25s; column replay (rare, per-lane atomic);
// rt merged across halves (shfl_xor 32); row replay vs final rt (ascending
// n, strict > = first-max within half); cross-half argmax via packed
// (iou_bits<<32)|(NN-bi) max; h==0 lane writes the slot.
// ---------------------------------------------------------------------------
__global__ __launch_bounds__(256, 8) void iou_half_kernel(
        const float4* __restrict__ anchors_xyxy,    // A
        const float4* __restrict__ tab_ro,          // B*N records (read)
        float* tab_at,                              // same base (atomics)
        unsigned long long* __restrict__ colmax,    // B*N packed, prior-init
        int* __restrict__ out_slot)                 // -> out[5BA..6BA)
{
    const int tid  = threadIdx.x;
    const int lane = tid & 63;
    const int slot = blockIdx.x * 4 + (tid >> 6);
    const int t0 = (slot * NWT) >> 13;
    const int t1 = ((slot + 1) * NWT) >> 13;
    const int lrow = lane & 31;                     // row offset in task
    const int h    = lane >> 5;                     // half: gts [50h,50h+50)
    const int n0   = h * 50;

    for (int t = t0; t < t1; t++) {
        const int r = t * 32 + lrow;                // flat row in [0, B*A)
        const int b = r / AA;                       // const-div -> magic mul
        const int a = r - b * AA;
        const float4 axy = anchors_xyxy[a];
        const float area_a = (axy.z - axy.x) * (axy.w - axy.y);
        const unsigned lowkey = (unsigned)(AA - a); // bigger = lower anchor
        const float4* __restrict__ tb = tab_ro + (size_t)b * NN * 2;
        float* tbat = tab_at + (size_t)b * NN * 8;
        unsigned long long* cmx = colmax + (size_t)b * NN;

        // ---------------- Phase A: two branchless 25-chunks ---------------
        float rt = RT_SEED;        // (qa >= rt) implies qa > 0
        unsigned rm0 = 0, cm0 = 0, rm1 = 0, cm1 = 0;
        chunk25(axy, area_a, tb, n0,      rt, rm0, cm0);
        chunk25(axy, area_a, tb, n0 + 25, rt, rm1, cm1);

        // ---------------- column replay (rare after prior priming) --------
        unsigned cms[2] = {cm0, cm1};
        #pragma unroll
        for (int hh = 0; hh < 2; hh++) {
            unsigned c = cms[hh];
            const int nb = n0 + hh * 25;
            while (c) {
                int n = __builtin_ctz(c) + nb;
                c &= c - 1;
                float inter, uni;
                geom(axy, tb[n * 2], area_a, tb[n * 2 + 1].x, inter, uni);
                float iou = inter / uni;             // exact IEEE == numpy
                atomicMax(cmx + n,
                    (((unsigned long long)__float_as_uint(iou)) << 32) |
                    (unsigned long long)lowkey);
                atomicMax((unsigned*)(tbat + n * 8 + 5),  // scurf warm-up
                          __float_as_uint(iou * DEFL));
            }
        }

        // ---------------- merge rt across the row's two halves ------------
        rt = fmaxf(rt, __shfl_xor(rt, 32));

        // ---------------- Phase B: replay own records vs final rt ---------
        float bv = 0.0f;   // default (0, bi=0) == numpy all-zero row
        int bi = 0;
        unsigned rms[2] = {rm0, rm1};
        #pragma unroll
        for (int hh = 0; hh < 2; hh++) {
            unsigned m = rms[hh];
            const int nb = n0 + hh * 25;
            while (m) {
                int n = __builtin_ctz(m) + nb;
                m &= m - 1;
                float inter, uni;
                geom(axy, tb[n * 2], area_a, tb[n * 2 + 1].x, inter, uni);
                float qa = inter * __builtin_amdgcn_rcpf(uni);
                if (qa >= rt) {                      // final-threshold re-test
                    float iou = inter / uni;         // exact IEEE == numpy
                    if (iou > bv) { bv = iou; bi = n; } // strict >: first max
                }
            }
        }

        // ---------------- cross-half argmax (first-max tie rule) ----------
        unsigned long long k =
            (((unsigned long long)__float_as_uint(bv)) << 32) |
            (unsigned long long)(unsigned)(NN - bi);
        unsigned long long o = __shfl_xor(k, 32);
        k = o > k ? o : k;

        if (h == 0) {
            float fbv = __uint_as_float((unsigned)(k >> 32));
            int   fbi = NN - (int)(k & 0xFFFFFFFFull);
            // pos decision folded into the slot: exact fbv vs 0.5 (override
            // applied later via OVR table / OVR_FLAG).
            out_slot[(size_t)b * AA + a] = fbi | (fbv > 0.5f ? POS_BIT : 0);
        }
    }
}

// ---------------------------------------------------------------------------
// FUSED encode: scatter folded in via LDS override table (needs colmax in
// ws, outside the boxes region encode overwrites). ovr[rel] = max n whose
// column winner is anchor abase+rel (atomicMax == np last-n-wins). low==0
// prior sentinel rejected by the low>=1 guard.
// ---------------------------------------------------------------------------
__global__ __launch_bounds__(256) void encode_fused_kernel(
        const int* __restrict__ gt_labels,
        const float4* __restrict__ gt_boxes,        // xyxy
        const float4* __restrict__ anchors_cxcywh,
        const unsigned long long* __restrict__ colmax,
        float* __restrict__ out)
{
    const int b = blockIdx.y;
    const int tid = threadIdx.x;
    const int abase = blockIdx.x * 256;

    __shared__ float4 sg[NN];
    __shared__ int    slab[NN];
    __shared__ int    ovr[256];

    ovr[tid] = -1;
    if (tid < NN) {
        sg[tid]   = gt_boxes[b * NN + tid];
        slab[tid] = gt_labels[b * NN + tid];
    }
    __syncthreads();
    if (tid < NN) {
        unsigned long long v = colmax[b * NN + tid];
        unsigned low = (unsigned)(v & 0xFFFFFFFFull);
        if (low >= 1u && low <= (unsigned)AA) {
            int rel = (AA - (int)low) - abase;       // column-winner anchor
            if (rel >= 0 && rel < 256) atomicMax(&ovr[rel], tid);
        }
    }
    __syncthreads();

    const int a = abase + tid;
    if (a >= AA) return;

    const size_t BA = (size_t)BB * AA;
    const size_t base = (size_t)b * AA + a;

    int s = ((const int*)(out + 5 * BA))[base];
    int o = ovr[tid];

    int idx; bool pos;
    if (o >= 0) { idx = o;          pos = true; }
    else        { idx = s & 0x7FFF; pos = (s & POS_BIT) != 0; }

    const float4 g = sg[idx];
    const float gcx = (g.x + g.z) * 0.5f;
    const float gcy = (g.y + g.w) * 0.5f;
    const float gw  = g.z - g.x;
    const float gh  = g.w - g.y;

    const float4 anc = anchors_cxcywh[a];
    const float ecx = (gcx - anc.x) / anc.z;
    const float ecy = (gcy - anc.y) / anc.w;
    const float ew  = logf((gw + EPS_F) / (anc.z + EPS_F));
    const float eh  = logf((gh + EPS_F) / (anc.w + EPS_F));

    out[base] = pos ? (float)slab[idx] : 0.0f;                   // labels
    ((float4*)(out + BA))[base] = make_float4(ecx, ecy, ew, eh); // boxes
    out[5 * BA + base] = pos ? 1.0f : 0.0f;                      // mask
}

// ---------------------------------------------------------------------------
// Fallback scatter + encode (HW-proven): used when ws_size < 51,200 B and
// colmax must alias out's boxes region (consumed before encode overwrites).
// ---------------------------------------------------------------------------
__global__ void scatter_kernel(const unsigned long long* __restrict__ colmax,
                               int* __restrict__ out_slot) {
    const int b = blockIdx.x;
    const int n = threadIdx.x;
    if (n < NN) {
        unsigned long long v = colmax[b * NN + n];
        unsigned low = (unsigned)(v & 0xFFFFFFFFull);
        if (low >= 1u && low <= (unsigned)AA) {
            int idx = AA - (int)low;
            atomicMax(&out_slot[(size_t)b * AA + idx], OVR_FLAG + n);
        }
    }
}

__global__ __launch_bounds__(256) void encode_kernel(
        const int* __restrict__ gt_labels,
        const float4* __restrict__ gt_boxes,        // xyxy
        const float4* __restrict__ anchors_cxcywh,
        float* __restrict__ out)
{
    const int b = blockIdx.y;
    const int tid = threadIdx.x;
    const int a = blockIdx.x * 256 + tid;

    __shared__ float4 sg[NN];
    __shared__ int    slab[NN];
    if (tid < NN) {
        sg[tid]   = gt_boxes[b * NN + tid];
        slab[tid] = gt_labels[b * NN + tid];
    }
    __syncthreads();
    if (a >= AA) return;

    const size_t BA = (size_t)BB * AA;
    const size_t base = (size_t)b * AA + a;

    int s = ((const int*)(out + 5 * BA))[base];

    int idx; bool pos;
    if (s >= OVR_FLAG) { idx = s - OVR_FLAG;  pos = true; }
    else               { idx = s & 0x7FFF;    pos = (s & POS_BIT) != 0; }

    const float4 g = sg[idx];
    const float gcx = (g.x + g.z) * 0.5f;
    const float gcy = (g.y + g.w) * 0.5f;
    const float gw  = g.z - g.x;
    const float gh  = g.w - g.y;

    const float4 anc = anchors_cxcywh[a];
    const float ecx = (gcx - anc.x) / anc.z;
    const float ecy = (gcy - anc.y) / anc.w;
    const float ew  = logf((gw + EPS_F) / (anc.z + EPS_F));
    const float eh  = logf((gh + EPS_F) / (anc.w + EPS_F));

    out[base] = pos ? (float)slab[idx] : 0.0f;                   // labels
    ((float4*)(out + BA))[base] = make_float4(ecx, ecy, ew, eh); // boxes
    out[5 * BA + base] = pos ? 1.0f : 0.0f;                      // mask
}

extern "C" void kernel_launch(void* const* d_in, const int* in_sizes, int n_in,
                              void* d_out, int out_size, void* d_ws, size_t ws_size,
                              hipStream_t stream) {
    const int*    gt_labels    = (const int*)d_in[0];
    const float4* gt_boxes     = (const float4*)d_in[1];
    const float4* anchors_cxcy = (const float4*)d_in[2];
    const float4* anchors_xyxy = (const float4*)d_in[3];
    float* out = (float*)d_out;

    const size_t BA = (size_t)BB * AA;
    int* slot = (int*)(out + 5 * BA);

    // Fused path needs colmax (B*N u64 = 51,200 B) outside out (engaged and
    // proven in round 2: ws >= 51,200). The 32B record table lives in out's
    // boxes region AFTER the fallback-colmax slot (only read by iou; encode
    // overwrites the boxes region last). Offsets identical in both paths.
    const bool fused = (ws_size >= (size_t)(BB * NN * 8));
    unsigned long long* colmax = fused
        ? (unsigned long long*)d_ws                  // 8B-aligned ws
        : (unsigned long long*)(out + BA);           // boxes region (proven)
    float* tabf = out + BA + (size_t)BB * NN * 2;    // skip 51,200 B
    float4* tab4 = (float4*)tabf;

    prior_kernel<<<BB, 128, 0, stream>>>(gt_boxes, anchors_xyxy, colmax, tab4);

    iou_half_kernel<<<2048, 256, 0, stream>>>(anchors_xyxy, tab4, tabf,
                                              colmax, slot);

    dim3 egrid(NTILE, BB);    // (35, 64)
    if (fused) {
        encode_fused_kernel<<<egrid, 256, 0, stream>>>(gt_labels, gt_boxes,
                                                       anchors_cxcy, colmax,
                                                       out);
    } else {
        scatter_kernel<<<BB, 128, 0, stream>>>(colmax, slot);
        encode_kernel<<<egrid, 256, 0, stream>>>(gt_labels, gt_boxes,
                                                 anchors_cxcy, out);
    }
}